// Round 1
// baseline (133.245 us; speedup 1.0000x reference)
//
#include <hip/hip_runtime.h>
#include <math.h>

// Problem geometry (fixed by setup_inputs)
#define NT    32
#define NA    64
#define NB    64
#define NGEO  128
#define NELEM (NT * NA * NB * NGEO)   // 16777216 = 2^24
#define TSHIFT 19                      // plane = NA*NB*NGEO = 2^19

// Per-point emission.
// Boundary-sensitive math (t_rot, r2) uses __f*_rn intrinsics to block
// hipcc's default -ffp-contract=fast, so mask decisions bit-match the
// numpy f32 reference ((x*x + y*y) + z*z, left-assoc, no fma; sqrtf is
// correctly rounded). Continuous-path math (sincos, weights, sigmoid)
// only needs ~2% relative accuracy.
__device__ __forceinline__ float emission_point(
    float x, float y, float z, float Om, float tg,
    float tM, float tinj, const float* __restrict__ grid)
{
    // t_rot = (t_M - t_geos) - t_injection   (exact order match)
    float t_rot = __fsub_rn(__fsub_rn(tM, tg), tinj);

    // r = sqrt((x*x + y*y) + z*z) in f32, no contraction
    float r2 = __fadd_rn(__fadd_rn(__fmul_rn(x, x), __fmul_rn(y, y)),
                         __fmul_rn(z, z));
    float r = sqrtf(r2);

    if (t_rot < 0.0f || r < 2.0f || r > 10.0f || fabsf(z) > 4.0f)
        return 0.0f;

    // warp-back rotation about z
    float theta = -Om * t_rot;
    float s, c;
    sincosf(theta, &s, &c);
    float xw = x * c - y * s;
    float yw = x * s + y * c;

    // to grid index space: (v + 10) / 20 * 63
    float fx = (xw + 10.0f) * 0.05f * 63.0f;
    float fy = (yw + 10.0f) * 0.05f * 63.0f;
    float fz = (z  + 10.0f) * 0.05f * 63.0f;

    float flx = floorf(fx), fly = floorf(fy), flz = floorf(fz);
    int ix0 = (int)flx, iy0 = (int)fly, iz0 = (int)flz;
    int ix1 = ix0 + 1, iy1 = iy0 + 1, iz1 = iz0 + 1;

    float wx1 = fx - flx, wy1 = fy - fly, wz1 = fz - flz;
    float wx0 = 1.0f - wx1, wy0 = 1.0f - wy1, wz0 = 1.0f - wz1;

    // constant-mode (cval=0): zero the weight of any out-of-range side,
    // clamp addresses for memory safety (weight is already 0 there).
    float ax0 = ((unsigned)ix0 <= 63u) ? wx0 : 0.0f;
    float ax1 = ((unsigned)ix1 <= 63u) ? wx1 : 0.0f;
    float ay0 = ((unsigned)iy0 <= 63u) ? wy0 : 0.0f;
    float ay1 = ((unsigned)iy1 <= 63u) ? wy1 : 0.0f;
    float az0 = ((unsigned)iz0 <= 63u) ? wz0 : 0.0f;
    float az1 = ((unsigned)iz1 <= 63u) ? wz1 : 0.0f;

    int cx0 = min(max(ix0, 0), 63), cx1 = min(max(ix1, 0), 63);
    int cy0 = min(max(iy0, 0), 63), cy1 = min(max(iy1, 0), 63);
    int cz0 = min(max(iz0, 0), 63), cz1 = min(max(iz1, 0), 63);

    const float* g0 = grid + cx0 * 4096;
    const float* g1 = grid + cx1 * 4096;
    int b00 = cy0 * 64, b01 = cy1 * 64;

    float v000 = g0[b00 + cz0], v001 = g0[b00 + cz1];
    float v010 = g0[b01 + cz0], v011 = g0[b01 + cz1];
    float v100 = g1[b00 + cz0], v101 = g1[b00 + cz1];
    float v110 = g1[b01 + cz0], v111 = g1[b01 + cz1];

    float net = ax0 * (ay0 * (az0 * v000 + az1 * v001) +
                       ay1 * (az0 * v010 + az1 * v011)) +
                ax1 * (ay0 * (az0 * v100 + az1 * v101) +
                       ay1 * (az0 * v110 + az1 * v111));

    // sigmoid(net - 10)
    return 1.0f / (1.0f + expf(10.0f - net));
}

__global__ __launch_bounds__(256) void grid_predictor_kernel(
    const float* __restrict__ t_frames,
    const float* __restrict__ coords,   // 3 contiguous planes of NELEM
    const float* __restrict__ Omega,
    const float* __restrict__ t_geos,
    const float* __restrict__ t_inj,
    const float* __restrict__ t_start,
    const float* __restrict__ grid,
    float* __restrict__ out)
{
    int v = blockIdx.x * blockDim.x + threadIdx.x;
    long long i = (long long)v * 4;
    if (i >= NELEM) return;

    int t = (int)(i >> TSHIFT);                 // plane index (uniform per thread)
    float tM   = __fsub_rn(t_frames[t], t_start[0]);
    float tinj = t_inj[0];

    float4 x4 = *(const float4*)(coords + i);
    float4 y4 = *(const float4*)(coords + NELEM + i);
    float4 z4 = *(const float4*)(coords + 2LL * NELEM + i);
    float4 o4 = *(const float4*)(Omega + i);
    float4 g4 = *(const float4*)(t_geos + i);

    float4 r;
    r.x = emission_point(x4.x, y4.x, z4.x, o4.x, g4.x, tM, tinj, grid);
    r.y = emission_point(x4.y, y4.y, z4.y, o4.y, g4.y, tM, tinj, grid);
    r.z = emission_point(x4.z, y4.z, z4.z, o4.z, g4.z, tM, tinj, grid);
    r.w = emission_point(x4.w, y4.w, z4.w, o4.w, g4.w, tM, tinj, grid);

    *(float4*)(out + i) = r;
}

extern "C" void kernel_launch(void* const* d_in, const int* in_sizes, int n_in,
                              void* d_out, int out_size, void* d_ws, size_t ws_size,
                              hipStream_t stream) {
    const float* t_frames = (const float*)d_in[0];
    const float* coords   = (const float*)d_in[1];
    const float* Omega    = (const float*)d_in[2];
    const float* t_geos   = (const float*)d_in[3];
    const float* t_inj    = (const float*)d_in[4];
    const float* t_start  = (const float*)d_in[5];
    const float* grid     = (const float*)d_in[6];
    float* out = (float*)d_out;

    const int threads = 256;
    const int nvec = NELEM / 4;                 // 4 elements per thread
    const int blocks = (nvec + threads - 1) / threads;   // 16384
    grid_predictor_kernel<<<blocks, threads, 0, stream>>>(
        t_frames, coords, Omega, t_geos, t_inj, t_start, grid, out);
}